// Round 9
// baseline (74.259 us; speedup 1.0000x reference)
//
#include <hip/hip_runtime.h>

// ---------- types ----------
typedef __attribute__((ext_vector_type(4))) float float4_;
typedef __attribute__((ext_vector_type(4))) float f32x4;
typedef __attribute__((ext_vector_type(8))) int   i32x8;

#define NROWS 8192
#define NKEYS 16384
#define DDIM  256

// exp(x/T) == exp2(x * C_SC)
static constexpr float T_INV = (float)(1.0 / 0.07);
static constexpr float C_SC  = (float)(1.0 / (0.07 * 0.6931471805599453));

// ---------------------------------------------------------------------------
// fp8 chunk-image swizzle, 32B granularity: byte offset of 32B-group g32
// (0..7) of row r (0..127) inside one 32KB chunk image (128 keys x 256 B).
// Used by BOTH prep (global write) and gemm (ds_read after LINEAR
// global_load_lds copy) — rule #21: one function, both sides.
// Bank math (2x ds_read_b128 per 32B): 16 lanes sharing l4 have r = base+l15
// -> r&7 covers 0..7 twice -> g32' = g32^(r&7) hits all 8 distinct 32B slots
// twice -> 32 banks, 2 lanes/bank = free (m136).
// Note swz32(r+64,g) = swz32(r,g)+16384 (XOR only uses r&7) -> colt stride.
// ---------------------------------------------------------------------------
__device__ __forceinline__ int swz32(int r, int g32) {
  return (r << 8) + (((g32 ^ (r & 7)) & 7) << 5);
}

// ---------------------------------------------------------------------------
// Kernel 1: normalize rows; emit fp8 e4m3 (OCP, HW cvt):
//   qs8  [8192][256] fp8: normalized q scaled by C_SC (MFMA A), natural.
//   keys8: 128 chunk images of 32KB: key k -> image (k>>7), row k&127,
//          dword at swz32(r, d>>5) + (d&31). Keys 0..8191 = q, 8192.. = g.
//   Pterm[row] = dot_f32(q,g)/T ; diagsub[row] = exp2(dot_f32 of the
//   fp8-ROUNDED qs8[i]·q8[i]) — exact qq-diagonal cancellation.
// Also zeroes S.
// ---------------------------------------------------------------------------
__global__ __launch_bounds__(256) void prep_kernel(
    const float* __restrict__ h, const float* __restrict__ g,
    unsigned int* __restrict__ qs8, unsigned int* __restrict__ keys8,
    float* __restrict__ Pterm, float* __restrict__ diagsub,
    float* __restrict__ S)
{
  const int row  = blockIdx.x * 4 + (threadIdx.x >> 6);
  const int lane = threadIdx.x & 63;       // 4 dims each
  float4_ hv = *((const float4_*)h + row * 64 + lane);
  float4_ gv = *((const float4_*)g + row * 64 + lane);

  float ssh = hv.x*hv.x + hv.y*hv.y + hv.z*hv.z + hv.w*hv.w;
  float ssg = gv.x*gv.x + gv.y*gv.y + gv.z*gv.z + gv.w*gv.w;
#pragma unroll
  for (int m = 1; m < 64; m <<= 1) {
    ssh += __shfl_xor(ssh, m);
    ssg += __shfl_xor(ssg, m);
  }
  const float sh = 1.0f / fmaxf(sqrtf(ssh), 1e-8f);
  const float sg = 1.0f / fmaxf(sqrtf(ssg), 1e-8f);

  float qn[4] = { hv.x*sh, hv.y*sh, hv.z*sh, hv.w*sh };
  float gn[4] = { gv.x*sg, gv.y*sg, gv.z*sg, gv.w*sg };

  float pd = qn[0]*gn[0] + qn[1]*gn[1] + qn[2]*gn[2] + qn[3]*gn[3];

  // fp8 packs (RNE, saturating). word_sel / byte_sel must be literals.
  int pq = __builtin_amdgcn_cvt_pk_fp8_f32(qn[0], qn[1], 0, 0);
  pq     = __builtin_amdgcn_cvt_pk_fp8_f32(qn[2], qn[3], pq, 1);
  int ps = __builtin_amdgcn_cvt_pk_fp8_f32(qn[0]*C_SC, qn[1]*C_SC, 0, 0);
  ps     = __builtin_amdgcn_cvt_pk_fp8_f32(qn[2]*C_SC, qn[3]*C_SC, ps, 1);
  int pg = __builtin_amdgcn_cvt_pk_fp8_f32(gn[0], gn[1], 0, 0);
  pg     = __builtin_amdgcn_cvt_pk_fp8_f32(gn[2], gn[3], pg, 1);

  float dd =
      __builtin_amdgcn_cvt_f32_fp8(ps, 0) * __builtin_amdgcn_cvt_f32_fp8(pq, 0)
    + __builtin_amdgcn_cvt_f32_fp8(ps, 1) * __builtin_amdgcn_cvt_f32_fp8(pq, 1)
    + __builtin_amdgcn_cvt_f32_fp8(ps, 2) * __builtin_amdgcn_cvt_f32_fp8(pq, 2)
    + __builtin_amdgcn_cvt_f32_fp8(ps, 3) * __builtin_amdgcn_cvt_f32_fp8(pq, 3);

#pragma unroll
  for (int m = 1; m < 64; m <<= 1) {
    pd += __shfl_xor(pd, m);
    dd += __shfl_xor(dd, m);
  }

  qs8[(size_t)row * 64 + lane] = (unsigned int)ps;   // natural, coalesced

  char* kb = (char*)keys8;
  const int g32 = lane >> 3;               // 32B group 0..7
  const int sub = (lane & 7) << 2;         // dword within group
  {
    const int k = row;
    *(unsigned int*)(kb + (((size_t)(k >> 7)) << 15)
                     + swz32(k & 127, g32) + sub) = (unsigned int)pq;
  }
  {
    const int k = NROWS + row;
    *(unsigned int*)(kb + (((size_t)(k >> 7)) << 15)
                     + swz32(k & 127, g32) + sub) = (unsigned int)pg;
  }

  if (lane == 0) {
    Pterm[row]   = pd * T_INV;
    diagsub[row] = __builtin_amdgcn_exp2f(dd);
    S[row]       = 0.0f;
  }
}

// ---------------------------------------------------------------------------
// Kernel 2: fused MX-fp8 GEMM (K=128/instr, scale=1.0) + exp2 + row-sum.
// Grid 256 = 64 M-tiles (BM=128) x 4 key-slices (4096 keys = 32 chunks of
// 128). slice = bid & 3 (XCD-resident: bid%8 fixes bid&3 per XCD).
// vs r8: 32KB chunks -> 64KB LDS/block -> TWO blocks/CU co-resident
// (VGPR 116 <= 128 allows 16 waves/CU; launch_bounds(512,4) enforces).
// Cross-block overlap fills each block's barrier/harvest gaps — the ~40%
// lockstep dead time r8's counters exposed (MfmaUtil 28% @ 1 block/CU).
// ---------------------------------------------------------------------------
typedef __attribute__((address_space(1))) const unsigned int gu32;
typedef __attribute__((address_space(3))) unsigned int       lu32;

__global__ __launch_bounds__(512, 4) void nce_gemm(
    const unsigned int* __restrict__ qs8,
    const unsigned int* __restrict__ keys8,
    float* __restrict__ S)
{
  __shared__ __align__(16) char lds_k[2 * 32768];    // 64 KB double buffer

  const int tid  = threadIdx.x;
  const int wid  = tid >> 6;
  const int lane = tid & 63;
  const int l15  = lane & 15, l4 = lane >> 4;

  const int bid   = blockIdx.x;
  const int slice = bid & 3;               // constant per XCD
  const int mtile = bid >> 2;              // 0..63

  const int wm = wid >> 2;                 // 0..1
  const int wn = wid & 3;                  // 0..3
  const int m0 = mtile * 128 + wm * 64;

  // ---- A fragments: 32B of K per (mf, kk); K elem = kk*128 + l4*32 + j ----
  const char* qb = (const char*)qs8;
  i32x8 a8[4][2];
#pragma unroll
  for (int mf = 0; mf < 4; ++mf) {
    const char* rp = qb + (size_t)(m0 + mf * 16 + l15) * 256 + l4 * 32;
#pragma unroll
    for (int kk = 0; kk < 2; ++kk)
      a8[mf][kk] = *(const i32x8*)(rp + kk * 128);
  }

  // per-chunk loop-invariant ds_read offsets for colt==0 (colt adds 16384)
  const int rr0 = wn * 16 + l15;           // key row within chunk, colt 0
  int boff0[2];
#pragma unroll
  for (int kk = 0; kk < 2; ++kk)
    boff0[kk] = swz32(rr0, kk * 4 + l4);

  const f32x4 zero4 = { 0.f, 0.f, 0.f, 0.f };
  f32x4 acc[2][4];                         // [colt][mf]
  float Sp[4][4] = {};                     // [mf][q] row-sums

  const char* kbytes = (const char*)keys8;

  // stage chunk c (32KB image) linearly into LDS buffer c&1
  auto stage = [&](int c) {
    const char* src = kbytes + (((size_t)(slice * 32 + c)) << 15);
    char* dst = lds_k + (c & 1) * 32768;
#pragma unroll
    for (int i = 0; i < 4; ++i) {
      const int sub = (i << 3) + wid;      // 1KB sub-chunk 0..31
      __builtin_amdgcn_global_load_lds(
          (gu32*)(src + (sub << 10) + (lane << 4)),
          (lu32*)(dst + (sub << 10)),
          16, 0, 0);
    }
  };

  stage(0);
  for (int c = 0; c < 32; ++c) {
    __syncthreads();                       // chunk c landed; buf (c-1) free
    if (c + 1 < 32) stage(c + 1);          // async across whole chunk

    const char* lb = lds_k + (c & 1) * 32768;
#pragma unroll
    for (int colt = 0; colt < 2; ++colt) {
      i32x8 b8[2];
#pragma unroll
      for (int kk = 0; kk < 2; ++kk)
        b8[kk] = *(const i32x8*)(lb + boff0[kk] + colt * 16384);

      if (colt == 0 && c > 0) {            // harvest prev chunk under latency
#pragma unroll
        for (int ct = 0; ct < 2; ++ct)
#pragma unroll
          for (int mf = 0; mf < 4; ++mf)
#pragma unroll
            for (int q = 0; q < 4; ++q)
              Sp[mf][q] += __builtin_amdgcn_exp2f(acc[ct][mf][q]);
      }

      // cbsz=0 (A fmt fp8 e4m3), blgp=0 (B fmt fp8), scales 127 = x1.0
#pragma unroll
      for (int kk = 0; kk < 2; ++kk)
#pragma unroll
        for (int mf = 0; mf < 4; ++mf)
          acc[colt][mf] = __builtin_amdgcn_mfma_scale_f32_16x16x128_f8f6f4(
              a8[mf][kk], b8[kk], kk == 0 ? zero4 : acc[colt][mf],
              0, 0, 0, 127, 0, 127);
    }
  }
#pragma unroll
  for (int ct = 0; ct < 2; ++ct)           // last chunk's harvest
#pragma unroll
    for (int mf = 0; mf < 4; ++mf)
#pragma unroll
      for (int q = 0; q < 4; ++q)
        Sp[mf][q] += __builtin_amdgcn_exp2f(acc[ct][mf][q]);

  // reduce across the 16 columns (lanes sharing l4), then one atomic/row
#pragma unroll
  for (int mf = 0; mf < 4; ++mf)
#pragma unroll
    for (int q = 0; q < 4; ++q) {
      float v = Sp[mf][q];
      v += __shfl_xor(v, 1); v += __shfl_xor(v, 2);
      v += __shfl_xor(v, 4); v += __shfl_xor(v, 8);
      Sp[mf][q] = v;
    }
  if (l15 == 0) {
#pragma unroll
    for (int mf = 0; mf < 4; ++mf)
#pragma unroll
      for (int q = 0; q < 4; ++q)
        atomicAdd(&S[m0 + mf * 16 + l4 * 4 + q], Sp[mf][q]);
  }
}

// ---------------------------------------------------------------------------
// Kernel 3: loss = mean_i [ log(S_i - diagsub_i) - Pterm_i ]
// ---------------------------------------------------------------------------
__global__ __launch_bounds__(256) void finalize_kernel(
    const float* __restrict__ S, const float* __restrict__ Pterm,
    const float* __restrict__ diagsub, float* __restrict__ out)
{
  const int tid = threadIdx.x;
  float acc = 0.0f;
  for (int i = tid; i < NROWS; i += 256) {
    float v = S[i] - diagsub[i];
    acc += logf(fmaxf(v, 1e-20f)) - Pterm[i];
  }
#pragma unroll
  for (int m = 1; m < 64; m <<= 1) acc += __shfl_xor(acc, m);
  __shared__ float w[4];
  if ((tid & 63) == 0) w[tid >> 6] = acc;
  __syncthreads();
  if (tid == 0) out[0] = (w[0] + w[1] + w[2] + w[3]) * (1.0f / (float)NROWS);
}

// ---------------------------------------------------------------------------
extern "C" void kernel_launch(void* const* d_in, const int* in_sizes, int n_in,
                              void* d_out, int out_size, void* d_ws, size_t ws_size,
                              hipStream_t stream) {
  const float* h  = (const float*)d_in[0];
  const float* hg = (const float*)d_in[1];

  char* ws = (char*)d_ws;
  const size_t OFF_QS   = 0;                      // 2 MB (8192*256 fp8)
  const size_t OFF_KEYS = (size_t)2 << 20;        // 4 MB (16384*256 fp8)
  const size_t OFF_P    = (size_t)6 << 20;        // 32 KB
  const size_t OFF_DIAG = OFF_P + 32 * 1024;      // 32 KB
  const size_t OFF_S    = OFF_DIAG + 32 * 1024;   // 32 KB
  const size_t NEED     = OFF_S + 32 * 1024;
  if (ws_size < NEED) return;

  unsigned int* qs8   = (unsigned int*)(ws + OFF_QS);
  unsigned int* keys8 = (unsigned int*)(ws + OFF_KEYS);
  float* Pterm   = (float*)(ws + OFF_P);
  float* diagsub = (float*)(ws + OFF_DIAG);
  float* S       = (float*)(ws + OFF_S);

  prep_kernel<<<2048, 256, 0, stream>>>(h, hg, qs8, keys8, Pterm, diagsub, S);
  nce_gemm<<<256, 512, 0, stream>>>(qs8, keys8, S);
  finalize_kernel<<<1, 256, 0, stream>>>(S, Pterm, diagsub, (float*)d_out);
}

// Round 10
// 63.414 us; speedup vs baseline: 1.1710x; 1.1710x over previous
//
#include <hip/hip_runtime.h>

// ---------- types ----------
typedef __attribute__((ext_vector_type(4))) float float4_;
typedef __attribute__((ext_vector_type(4))) float f32x4;
typedef __attribute__((ext_vector_type(8))) int   i32x8;

#define NROWS 8192
#define NKEYS 16384
#define DDIM  256

// exp(x/T) == exp2(x * C_SC)
static constexpr float T_INV = (float)(1.0 / 0.07);
static constexpr float C_SC  = (float)(1.0 / (0.07 * 0.6931471805599453));

// ---------------------------------------------------------------------------
// fp8 chunk-image swizzle, 32B granularity: byte offset of 32B-group g32
// (0..7) of row r (0..255) inside one 64KB chunk image (256 keys x 256 B).
// Used by BOTH prep (global write) and gemm (ds_read after LINEAR
// global_load_lds copy) — rule #21: one function, both sides.
// Bank math (2x ds_read_b128 per 32B): 16 lanes sharing l4 have r = base+l15
// -> r&7 covers 0..7 twice -> g32' = g32^(r&7) hits all 8 distinct 32B slots
// twice -> 32 banks, 2 lanes/bank = free (m136).
// swz32(r+64,g) = swz32(r,g)+16384 (XOR uses r&7 only) -> colt stride 16384.
// ---------------------------------------------------------------------------
__device__ __forceinline__ int swz32(int r, int g32) {
  return (r << 8) + (((g32 ^ (r & 7)) & 7) << 5);
}

// ---------------------------------------------------------------------------
// Kernel 1: normalize rows; emit fp8 e4m3 (OCP, HW cvt):
//   qs8  [8192][256] fp8: normalized q scaled by C_SC (MFMA A), natural.
//   keys8: 64 chunk images of 64KB: key k -> image (k>>8), row k&255,
//          dword at swz32(r, d>>5) + (d&31). Keys 0..8191 = q, 8192.. = g.
//   Pterm[row] = dot_f32(q,g)/T ; diagsub[row] = exp2(dot_f32 of the
//   fp8-ROUNDED qs8[i]·q8[i]) — exact qq-diagonal cancellation.
// Also zeroes S.
// ---------------------------------------------------------------------------
__global__ __launch_bounds__(256) void prep_kernel(
    const float* __restrict__ h, const float* __restrict__ g,
    unsigned int* __restrict__ qs8, unsigned int* __restrict__ keys8,
    float* __restrict__ Pterm, float* __restrict__ diagsub,
    float* __restrict__ S)
{
  const int row  = blockIdx.x * 4 + (threadIdx.x >> 6);
  const int lane = threadIdx.x & 63;       // 4 dims each
  float4_ hv = *((const float4_*)h + row * 64 + lane);
  float4_ gv = *((const float4_*)g + row * 64 + lane);

  float ssh = hv.x*hv.x + hv.y*hv.y + hv.z*hv.z + hv.w*hv.w;
  float ssg = gv.x*gv.x + gv.y*gv.y + gv.z*gv.z + gv.w*gv.w;
#pragma unroll
  for (int m = 1; m < 64; m <<= 1) {
    ssh += __shfl_xor(ssh, m);
    ssg += __shfl_xor(ssg, m);
  }
  const float sh = 1.0f / fmaxf(sqrtf(ssh), 1e-8f);
  const float sg = 1.0f / fmaxf(sqrtf(ssg), 1e-8f);

  float qn[4] = { hv.x*sh, hv.y*sh, hv.z*sh, hv.w*sh };
  float gn[4] = { gv.x*sg, gv.y*sg, gv.z*sg, gv.w*sg };

  float pd = qn[0]*gn[0] + qn[1]*gn[1] + qn[2]*gn[2] + qn[3]*gn[3];

  // fp8 packs (RNE, saturating). word_sel / byte_sel must be literals.
  int pq = __builtin_amdgcn_cvt_pk_fp8_f32(qn[0], qn[1], 0, 0);
  pq     = __builtin_amdgcn_cvt_pk_fp8_f32(qn[2], qn[3], pq, 1);
  int ps = __builtin_amdgcn_cvt_pk_fp8_f32(qn[0]*C_SC, qn[1]*C_SC, 0, 0);
  ps     = __builtin_amdgcn_cvt_pk_fp8_f32(qn[2]*C_SC, qn[3]*C_SC, ps, 1);
  int pg = __builtin_amdgcn_cvt_pk_fp8_f32(gn[0], gn[1], 0, 0);
  pg     = __builtin_amdgcn_cvt_pk_fp8_f32(gn[2], gn[3], pg, 1);

  float dd =
      __builtin_amdgcn_cvt_f32_fp8(ps, 0) * __builtin_amdgcn_cvt_f32_fp8(pq, 0)
    + __builtin_amdgcn_cvt_f32_fp8(ps, 1) * __builtin_amdgcn_cvt_f32_fp8(pq, 1)
    + __builtin_amdgcn_cvt_f32_fp8(ps, 2) * __builtin_amdgcn_cvt_f32_fp8(pq, 2)
    + __builtin_amdgcn_cvt_f32_fp8(ps, 3) * __builtin_amdgcn_cvt_f32_fp8(pq, 3);

#pragma unroll
  for (int m = 1; m < 64; m <<= 1) {
    pd += __shfl_xor(pd, m);
    dd += __shfl_xor(dd, m);
  }

  qs8[(size_t)row * 64 + lane] = (unsigned int)ps;   // natural, coalesced

  char* kb = (char*)keys8;
  const int g32 = lane >> 3;               // 32B group 0..7
  const int sub = (lane & 7) << 2;         // dword within group
  {
    const int k = row;
    *(unsigned int*)(kb + (((size_t)(k >> 8)) << 16)
                     + swz32(k & 255, g32) + sub) = (unsigned int)pq;
  }
  {
    const int k = NROWS + row;
    *(unsigned int*)(kb + (((size_t)(k >> 8)) << 16)
                     + swz32(k & 255, g32) + sub) = (unsigned int)pg;
  }

  if (lane == 0) {
    Pterm[row]   = pd * T_INV;
    diagsub[row] = __builtin_amdgcn_exp2f(dd);
    S[row]       = 0.0f;
  }
}

// ---------------------------------------------------------------------------
// Kernel 2: fused MX-fp8 GEMM (K=128/instr, scale=1.0) + exp2 + row-sum.
// Grid 256 = 64 M-tiles (BM=128) x 4 key-slices (4096 keys = 16 chunks of
// 256). slice = bid & 3 (XCD-resident). 8 waves (2m x 4n); r8 config
// (launch_bounds(512,1): VGPR 116, no spills — r9's (512,4) spilled to
// scratch at 8x WRITE_SIZE and never gained a co-resident block).
// vs r8: the 64-exp2 harvest is DISTRIBUTED per-colt and INTERLEAVED with
// the MFMA pairs. r8's counters showed pipe-sum behavior (MFMA 32% + LDS
// 22% + VALU 30% ≈ wall): clustered bursts stall the in-order wave on the
// backed-up matrix pipe while VALU idles. Interleaving lets each wave issue
// exp2/add into the ~34cy/instr matrix-pipe shadow and covers each colt's
// ds_read wait with the previous harvest slice.
// ---------------------------------------------------------------------------
typedef __attribute__((address_space(1))) const unsigned int gu32;
typedef __attribute__((address_space(3))) unsigned int       lu32;

__global__ __launch_bounds__(512, 1) void nce_gemm(
    const unsigned int* __restrict__ qs8,
    const unsigned int* __restrict__ keys8,
    float* __restrict__ S)
{
  __shared__ __align__(16) char lds_k[2 * 65536];    // 128 KB double buffer

  const int tid  = threadIdx.x;
  const int wid  = tid >> 6;
  const int lane = tid & 63;
  const int l15  = lane & 15, l4 = lane >> 4;

  const int bid   = blockIdx.x;
  const int slice = bid & 3;               // constant per XCD
  const int mtile = bid >> 2;              // 0..63

  const int wm = wid >> 2;                 // 0..1
  const int wn = wid & 3;                  // 0..3
  const int m0 = mtile * 128 + wm * 64;

  // ---- A fragments: 32B of K per (mf, kk); K elem = kk*128 + l4*32 + j ----
  const char* qb = (const char*)qs8;
  i32x8 a8[4][2];
#pragma unroll
  for (int mf = 0; mf < 4; ++mf) {
    const char* rp = qb + (size_t)(m0 + mf * 16 + l15) * 256 + l4 * 32;
#pragma unroll
    for (int kk = 0; kk < 2; ++kk)
      a8[mf][kk] = *(const i32x8*)(rp + kk * 128);
  }

  // per-chunk loop-invariant ds_read offsets for colt==0 (colt adds 16384)
  const int rr0 = wn * 16 + l15;           // key row within chunk, colt 0
  int boff0[2];
#pragma unroll
  for (int kk = 0; kk < 2; ++kk)
    boff0[kk] = swz32(rr0, kk * 4 + l4);

  const f32x4 zero4 = { 0.f, 0.f, 0.f, 0.f };
  f32x4 acc[4][4];                         // [colt][mf]
  float Sp[4][4] = {};                     // [mf][q] row-sums

  const char* kbytes = (const char*)keys8;

  // stage chunk c (64KB image) linearly into LDS buffer c&1
  auto stage = [&](int c) {
    const char* src = kbytes + (((size_t)(slice * 16 + c)) << 16);
    char* dst = lds_k + (c & 1) * 65536;
#pragma unroll
    for (int i = 0; i < 8; ++i) {
      const int sub = (i << 3) + wid;      // 1KB sub-chunk 0..63
      __builtin_amdgcn_global_load_lds(
          (gu32*)(src + (sub << 10) + (lane << 4)),
          (lu32*)(dst + (sub << 10)),
          16, 0, 0);
    }
  };

  stage(0);
  for (int c = 0; c < 16; ++c) {
    __syncthreads();                       // chunk c landed; buf (c-1) free
    if (c + 1 < 16) stage(c + 1);          // async across whole chunk

    const char* lb = lds_k + (c & 1) * 65536;
#pragma unroll
    for (int colt = 0; colt < 4; ++colt) {
      i32x8 b80 = *(const i32x8*)(lb + boff0[0] + colt * 16384);
      i32x8 b81 = *(const i32x8*)(lb + boff0[1] + colt * 16384);

      // interleave: per mf, harvest prev chunk's acc[colt][mf] (4 exp2 +
      // 4 adds, VALU) then the dependent MFMA pair (matrix pipe). exp2
      // reads the OLD acc before the kk0 MFMA rewrites it (renaming-safe).
#pragma unroll
      for (int mf = 0; mf < 4; ++mf) {
        if (c > 0) {
#pragma unroll
          for (int q = 0; q < 4; ++q)
            Sp[mf][q] += __builtin_amdgcn_exp2f(acc[colt][mf][q]);
        }
        // cbsz=0 (A fmt fp8 e4m3), blgp=0 (B fmt fp8), scales 127 = x1.0
        f32x4 t = __builtin_amdgcn_mfma_scale_f32_16x16x128_f8f6f4(
            a8[mf][0], b80, zero4, 0, 0, 0, 127, 0, 127);
        acc[colt][mf] = __builtin_amdgcn_mfma_scale_f32_16x16x128_f8f6f4(
            a8[mf][1], b81, t, 0, 0, 0, 127, 0, 127);
      }
    }
  }
#pragma unroll
  for (int ct = 0; ct < 4; ++ct)           // last chunk's harvest
#pragma unroll
    for (int mf = 0; mf < 4; ++mf)
#pragma unroll
      for (int q = 0; q < 4; ++q)
        Sp[mf][q] += __builtin_amdgcn_exp2f(acc[ct][mf][q]);

  // reduce across the 16 columns (lanes sharing l4), then one atomic/row
#pragma unroll
  for (int mf = 0; mf < 4; ++mf)
#pragma unroll
    for (int q = 0; q < 4; ++q) {
      float v = Sp[mf][q];
      v += __shfl_xor(v, 1); v += __shfl_xor(v, 2);
      v += __shfl_xor(v, 4); v += __shfl_xor(v, 8);
      Sp[mf][q] = v;
    }
  if (l15 == 0) {
#pragma unroll
    for (int mf = 0; mf < 4; ++mf)
#pragma unroll
      for (int q = 0; q < 4; ++q)
        atomicAdd(&S[m0 + mf * 16 + l4 * 4 + q], Sp[mf][q]);
  }
}

// ---------------------------------------------------------------------------
// Kernel 3: loss = mean_i [ log(S_i - diagsub_i) - Pterm_i ]
// ---------------------------------------------------------------------------
__global__ __launch_bounds__(256) void finalize_kernel(
    const float* __restrict__ S, const float* __restrict__ Pterm,
    const float* __restrict__ diagsub, float* __restrict__ out)
{
  const int tid = threadIdx.x;
  float acc = 0.0f;
  for (int i = tid; i < NROWS; i += 256) {
    float v = S[i] - diagsub[i];
    acc += logf(fmaxf(v, 1e-20f)) - Pterm[i];
  }
#pragma unroll
  for (int m = 1; m < 64; m <<= 1) acc += __shfl_xor(acc, m);
  __shared__ float w[4];
  if ((tid & 63) == 0) w[tid >> 6] = acc;
  __syncthreads();
  if (tid == 0) out[0] = (w[0] + w[1] + w[2] + w[3]) * (1.0f / (float)NROWS);
}

// ---------------------------------------------------------------------------
extern "C" void kernel_launch(void* const* d_in, const int* in_sizes, int n_in,
                              void* d_out, int out_size, void* d_ws, size_t ws_size,
                              hipStream_t stream) {
  const float* h  = (const float*)d_in[0];
  const float* hg = (const float*)d_in[1];

  char* ws = (char*)d_ws;
  const size_t OFF_QS   = 0;                      // 2 MB (8192*256 fp8)
  const size_t OFF_KEYS = (size_t)2 << 20;        // 4 MB (16384*256 fp8)
  const size_t OFF_P    = (size_t)6 << 20;        // 32 KB
  const size_t OFF_DIAG = OFF_P + 32 * 1024;      // 32 KB
  const size_t OFF_S    = OFF_DIAG + 32 * 1024;   // 32 KB
  const size_t NEED     = OFF_S + 32 * 1024;
  if (ws_size < NEED) return;

  unsigned int* qs8   = (unsigned int*)(ws + OFF_QS);
  unsigned int* keys8 = (unsigned int*)(ws + OFF_KEYS);
  float* Pterm   = (float*)(ws + OFF_P);
  float* diagsub = (float*)(ws + OFF_DIAG);
  float* S       = (float*)(ws + OFF_S);

  prep_kernel<<<2048, 256, 0, stream>>>(h, hg, qs8, keys8, Pterm, diagsub, S);
  nce_gemm<<<256, 512, 0, stream>>>(qs8, keys8, S);
  finalize_kernel<<<1, 256, 0, stream>>>(S, Pterm, diagsub, (float*)d_out);
}